// Round 4
// baseline (115.239 us; speedup 1.0000x reference)
//
#include <hip/hip_runtime.h>
#include <math.h>

#define Bb   64
#define Nn   8192
#define Dd   64
#define Cc   256
#define INn  128
#define CTRL 192
#define OUTW 320
#define EPSF 1e-8f
#define BN   (Bb*Nn)

// ---------------- workspace layout (floats) ----------------
#define OFF_XW 0                      // beta_w * sim_w           [B*N]
#define OFF_DR (1*BN)                 // mem . k_r                [B*N]
#define OFF_C5 (2*BN)                 // sum m e k_r              [B*N]
#define OFF_NQ (3*BN)                 // |mem|^2                  [B*N]
#define OFF_E1 (4*BN)                 // sum(ma - m^2 e)          [B*N]
#define OFF_E2 (5*BN)                 // sum(m^2e^2 - 2mae)       [B*N]
#define OFF_WW (6*BN)                 // write weights            [B*N]
#define OFF_WR (7*BN)                 // read weights             [B*N]
#define OFF_PT (8*BN)                 // read-vec partials        [2048*64]
#define OFF_BM (OFF_PT + 2048*64)     // per-block max of x_w     [512]
#define OFF_ER (OFF_BM + 512)         // erase (post-sigmoid)     [B*D]
#define OFF_AD (OFF_ER + Bb*Dd)       // add (post-tanh)          [B*D]
#define OFF_SC (OFF_AD + Bb*Dd)       // per-b scalars            [B*16]
// per-b scalars: 0..3 beta_w,g_w,gam_w,knorm_w | 4..7 beta_r,g_r,gam_r,knorm_r
//                8..10 s_w | 11 AK=a.k_r | 12..14 s_r | 15 A2=|a|^2

__device__ __forceinline__ float softplusf(float x) {
    return (x > 20.f) ? x : log1pf(__expf(x));
}
__device__ __forceinline__ float sigmoidf(float x) {
    return 1.f / (1.f + __expf(-x));
}

// ---- block reductions for 1024 threads (16 waves), red[16] LDS ----
__device__ __forceinline__ float blockSum1024(float v, float* red) {
    #pragma unroll
    for (int m = 32; m >= 1; m >>= 1) v += __shfl_xor(v, m);
    __syncthreads();
    if ((threadIdx.x & 63) == 0) red[threadIdx.x >> 6] = v;
    __syncthreads();
    float s = 0.f;
    #pragma unroll
    for (int i = 0; i < 16; ++i) s += red[i];
    return s;
}
__device__ __forceinline__ float blockMax1024(float v, float* red) {
    #pragma unroll
    for (int m = 32; m >= 1; m >>= 1) v = fmaxf(v, __shfl_xor(v, m));
    __syncthreads();
    if ((threadIdx.x & 63) == 0) red[threadIdx.x >> 6] = v;
    __syncthreads();
    float s = -1e30f;
    #pragma unroll
    for (int i = 0; i < 16; ++i) s = fmaxf(s, red[i]);
    return s;
}

struct MainArgs {
    const float *x, *prv, *Wc, *bc;
    const float *Wk_r, *bk_r, *Wb_r, *bb_r, *Wg_r, *bg_r, *Ws_r, *bs_r, *Wgam_r, *bgam_r;
    const float *Wk_w, *bk_w, *Wb_w, *bb_w, *Wg_w, *bg_w, *Ws_w, *bs_w, *Wgam_w, *bgam_w;
    const float *We_w, *be_w, *Wa_w, *ba_w;
    const float *mem;
    float *ws, *out;
};

// 512 blocks x 256 threads. Each block: redundant per-batch param compute,
// then streams 1024 rows of mem producing 6 per-row scalars + block max of x_w.
__global__ __launch_bounds__(256) void k_main(MainArgs a) {
    __shared__ float ci[CTRL];
    __shared__ float h[Cc];
    __shared__ alignas(16) float kbuf[128];   // [k_w | k_r]
    __shared__ alignas(16) float abuf[64];
    __shared__ alignas(16) float ebuf[64];
    __shared__ float red[4][16];
    __shared__ float sums[16];
    const int blk = blockIdx.x;
    const int b = blk >> 3;          // 8 blocks per batch
    const int chunk = blk & 7;
    const int t = threadIdx.x;

    // ---- redundant per-batch parameter computation ----
    if (t < INn)       ci[t] = a.x[b * INn + t];
    else if (t < CTRL) ci[t] = a.prv[b * Dd + (t - INn)];
    __syncthreads();

    float acc = a.bc[t];
    #pragma unroll 8
    for (int i = 0; i < CTRL; ++i) acc += ci[i] * a.Wc[i * Cc + t];
    const float hv = fmaxf(acc, 0.f);
    h[t] = hv;
    if (chunk == 0) a.out[b * OUTW + t] = hv;
    __syncthreads();

    {
        const int job = t >> 6, d = t & 63;
        const float* W  = (job == 0) ? a.Wk_w : (job == 1) ? a.Wk_r : (job == 2) ? a.We_w : a.Wa_w;
        const float* bs = (job == 0) ? a.bk_w : (job == 1) ? a.bk_r : (job == 2) ? a.be_w : a.ba_w;
        float p = bs[d];
        #pragma unroll 8
        for (int c = 0; c < Cc; ++c) p += h[c] * W[c * Dd + d];
        if (job == 0)      { kbuf[d] = p; }
        else if (job == 1) { kbuf[64 + d] = p; }
        else if (job == 2) { const float e = sigmoidf(p); ebuf[d] = e;
                             if (chunk == 0) a.ws[OFF_ER + b * Dd + d] = e; }
        else               { const float ad = tanhf(p); abuf[d] = ad;
                             if (chunk == 0) a.ws[OFF_AD + b * Dd + d] = ad; }
    }
    __syncthreads();

    float v[16];
    v[0] = hv * a.Wb_w[t];  v[1] = hv * a.Wg_w[t];  v[2] = hv * a.Wgam_w[t];
    v[3] = hv * a.Ws_w[t * 3 + 0]; v[4] = hv * a.Ws_w[t * 3 + 1]; v[5] = hv * a.Ws_w[t * 3 + 2];
    v[6] = hv * a.Wb_r[t];  v[7] = hv * a.Wg_r[t];  v[8] = hv * a.Wgam_r[t];
    v[9] = hv * a.Ws_r[t * 3 + 0]; v[10] = hv * a.Ws_r[t * 3 + 1]; v[11] = hv * a.Ws_r[t * 3 + 2];
    v[12] = (t < 64) ? kbuf[t] * kbuf[t] : 0.f;
    v[13] = (t >= 64 && t < 128) ? kbuf[t] * kbuf[t] : 0.f;
    v[14] = (t < 64) ? abuf[t] * kbuf[64 + t] : 0.f;
    v[15] = (t < 64) ? abuf[t] * abuf[t] : 0.f;
    #pragma unroll
    for (int k = 0; k < 16; ++k) {
        #pragma unroll
        for (int m = 32; m >= 1; m >>= 1) v[k] += __shfl_xor(v[k], m);
    }
    if ((t & 63) == 0) {
        #pragma unroll
        for (int k = 0; k < 16; ++k) red[t >> 6][k] = v[k];
    }
    __syncthreads();
    if (t < 16) sums[t] = red[0][t] + red[1][t] + red[2][t] + red[3][t];
    __syncthreads();

    if (chunk == 0 && t == 0) {
        float* sc = a.ws + OFF_SC + b * 16;
        sc[0] = softplusf(sums[0] + a.bb_w[0]);
        sc[1] = sigmoidf(sums[1] + a.bg_w[0]);
        sc[2] = softplusf(sums[2] + a.bgam_w[0]) + 1.f;
        sc[3] = sqrtf(sums[12]);
        sc[4] = softplusf(sums[6] + a.bb_r[0]);
        sc[5] = sigmoidf(sums[7] + a.bg_r[0]);
        sc[6] = softplusf(sums[8] + a.bgam_r[0]) + 1.f;
        sc[7] = sqrtf(sums[13]);
        {
            const float v0 = sums[3] + a.bs_w[0], v1 = sums[4] + a.bs_w[1], v2 = sums[5] + a.bs_w[2];
            const float m = fmaxf(fmaxf(v0, v1), v2);
            const float e0 = __expf(v0 - m), e1 = __expf(v1 - m), e2 = __expf(v2 - m);
            const float s = e0 + e1 + e2;
            sc[8] = e0 / s; sc[9] = e1 / s; sc[10] = e2 / s;
        }
        sc[11] = sums[14];
        {
            const float v0 = sums[9] + a.bs_r[0], v1 = sums[10] + a.bs_r[1], v2 = sums[11] + a.bs_r[2];
            const float m = fmaxf(fmaxf(v0, v1), v2);
            const float e0 = __expf(v0 - m), e1 = __expf(v1 - m), e2 = __expf(v2 - m);
            const float s = e0 + e1 + e2;
            sc[12] = e0 / s; sc[13] = e1 / s; sc[14] = e2 / s;
        }
        sc[15] = sums[15];
    }

    // beta_w / knorm_w needed by every thread for x_w
    const float beta = softplusf(sums[0] + a.bb_w[0]);
    const float kn   = sqrtf(sums[12]);

    // ---- streaming pass over this block's 1024 rows ----
    const int lane = t & 63;
    const int wv   = t >> 6;
    const int q = lane & 15, r = lane >> 4;
    const int wbase = blk * 1024 + wv * 256;        // 256 rows per wave

    const float4 kw = *(const float4*)(kbuf + (q << 2));
    const float4 kr = *(const float4*)(kbuf + 64 + (q << 2));
    const float4 ev = *(const float4*)(ebuf + (q << 2));
    const float4 av = *(const float4*)(abuf + (q << 2));
    float4 ekr; ekr.x = ev.x * kr.x; ekr.y = ev.y * kr.y; ekr.z = ev.z * kr.z; ekr.w = ev.w * kr.w;

    float* ws = a.ws;
    float lmax = -1e30f;
    #pragma unroll 4
    for (int it = 0; it < 64; ++it) {
        const int row = wbase + (it << 2) + r;
        const float4 m = *(const float4*)(a.mem + ((size_t)row << 6) + (q << 2));
        float dw, nq, dr, e1, e2, c5;
        {   const float mm = m.x * m.x, tt = mm * ev.x, ma = m.x * av.x;
            dw = m.x * kw.x; nq = mm; dr = m.x * kr.x;
            e1 = ma - tt; e2 = ev.x * (tt - 2.f * ma); c5 = m.x * ekr.x; }
        {   const float mm = m.y * m.y, tt = mm * ev.y, ma = m.y * av.y;
            dw = fmaf(m.y, kw.y, dw); nq += mm; dr = fmaf(m.y, kr.y, dr);
            e1 += ma - tt; e2 = fmaf(ev.y, tt - 2.f * ma, e2); c5 = fmaf(m.y, ekr.y, c5); }
        {   const float mm = m.z * m.z, tt = mm * ev.z, ma = m.z * av.z;
            dw = fmaf(m.z, kw.z, dw); nq += mm; dr = fmaf(m.z, kr.z, dr);
            e1 += ma - tt; e2 = fmaf(ev.z, tt - 2.f * ma, e2); c5 = fmaf(m.z, ekr.z, c5); }
        {   const float mm = m.w * m.w, tt = mm * ev.w, ma = m.w * av.w;
            dw = fmaf(m.w, kw.w, dw); nq += mm; dr = fmaf(m.w, kr.w, dr);
            e1 += ma - tt; e2 = fmaf(ev.w, tt - 2.f * ma, e2); c5 = fmaf(m.w, ekr.w, c5); }
        #pragma unroll
        for (int mk = 8; mk >= 1; mk >>= 1) {
            dw += __shfl_xor(dw, mk); nq += __shfl_xor(nq, mk);
            dr += __shfl_xor(dr, mk); e1 += __shfl_xor(e1, mk);
            e2 += __shfl_xor(e2, mk); c5 += __shfl_xor(c5, mk);
        }
        const float xw = beta * dw / (sqrtf(nq) * kn + EPSF);
        lmax = fmaxf(lmax, xw);
        if (q == 0) {
            ws[OFF_XW + row] = xw; ws[OFF_DR + row] = dr; ws[OFF_C5 + row] = c5;
            ws[OFF_NQ + row] = nq; ws[OFF_E1 + row] = e1; ws[OFF_E2 + row] = e2;
        }
    }
    // per-block max of x_w
    lmax = fmaxf(lmax, __shfl_xor(lmax, 16));
    lmax = fmaxf(lmax, __shfl_xor(lmax, 32));
    __syncthreads();
    if (lane == 0) red[0][wv] = lmax;
    __syncthreads();
    if (t == 0)
        ws[OFF_BM + blk] = fmaxf(fmaxf(red[0][0], red[0][1]), fmaxf(red[0][2], red[0][3]));
}

// fused W+R addressing: one block (1024 thr) per batch; thread t owns n in [8t, 8t+8)
__global__ __launch_bounds__(1024, 4) void k_addrBoth(float* __restrict__ ws,
                                                      const float* __restrict__ prevw_w,
                                                      const float* __restrict__ prevw_r) {
    __shared__ float buf[Nn];
    __shared__ float red[16];
    const int b = blockIdx.x, t = threadIdx.x;
    const int bN = b * Nn;
    const int base = t << 3;
    const float* sc = ws + OFF_SC + b * 16;
    const float g_w = sc[1], gam_w = sc[2];
    const float s0w = sc[8], s1w = sc[9], s2w = sc[10];
    const float beta_r = sc[4], g_r = sc[5], gam_r = sc[6], kn_r = sc[7];
    const float AK = sc[11], A2 = sc[15];
    const float s0r = sc[12], s1r = sc[13], s2r = sc[14];

    float M = -1e30f;
    #pragma unroll
    for (int i = 0; i < 8; ++i) M = fmaxf(M, ws[OFF_BM + b * 8 + i]);

    // ---- prefetch everything this block will need (hides latency under W-side) ----
    const float4 xw0 = *(const float4*)(ws + OFF_XW + bN + base);
    const float4 xw1 = *(const float4*)(ws + OFF_XW + bN + base + 4);
    const float4 pw0 = *(const float4*)(prevw_w + bN + base);
    const float4 pw1 = *(const float4*)(prevw_w + bN + base + 4);
    const float4 dr0 = *(const float4*)(ws + OFF_DR + bN + base);
    const float4 dr1 = *(const float4*)(ws + OFF_DR + bN + base + 4);
    const float4 c50 = *(const float4*)(ws + OFF_C5 + bN + base);
    const float4 c51 = *(const float4*)(ws + OFF_C5 + bN + base + 4);
    const float4 nq0 = *(const float4*)(ws + OFF_NQ + bN + base);
    const float4 nq1 = *(const float4*)(ws + OFF_NQ + bN + base + 4);
    const float4 e10 = *(const float4*)(ws + OFF_E1 + bN + base);
    const float4 e11 = *(const float4*)(ws + OFF_E1 + bN + base + 4);
    const float4 e20 = *(const float4*)(ws + OFF_E2 + bN + base);
    const float4 e21 = *(const float4*)(ws + OFF_E2 + bN + base + 4);
    const float4 pr0 = *(const float4*)(prevw_r + bN + base);
    const float4 pr1 = *(const float4*)(prevw_r + bN + base + 4);

    // ---------- W side ----------
    float xs[8];
    xs[0] = xw0.x; xs[1] = xw0.y; xs[2] = xw0.z; xs[3] = xw0.w;
    xs[4] = xw1.x; xs[5] = xw1.y; xs[6] = xw1.z; xs[7] = xw1.w;
    float pw[8];
    pw[0] = pw0.x; pw[1] = pw0.y; pw[2] = pw0.z; pw[3] = pw0.w;
    pw[4] = pw1.x; pw[5] = pw1.y; pw[6] = pw1.z; pw[7] = pw1.w;

    float lsum = 0.f;
    #pragma unroll
    for (int i = 0; i < 8; ++i) { const float e = __expf(xs[i] - M); xs[i] = e; lsum += e; }
    const float S = blockSum1024(lsum, red);
    const float sinv = 1.f / S;
    #pragma unroll
    for (int i = 0; i < 8; ++i) buf[base + i] = g_w * xs[i] * sinv + (1.f - g_w) * pw[i];
    __syncthreads();
    {
        float nb[10];
        nb[0] = buf[(base + Nn - 1) & (Nn - 1)];
        #pragma unroll
        for (int i = 0; i < 8; ++i) nb[i + 1] = buf[base + i];
        nb[9] = buf[(base + 8) & (Nn - 1)];
        float lps = 0.f;
        #pragma unroll
        for (int i = 0; i < 8; ++i) {
            const float wsv = s0w * nb[i + 2] + s1w * nb[i + 1] + s2w * nb[i];
            const float wp = __expf(gam_w * __logf(wsv));
            xs[i] = wp; lps += wp;
        }
        const float PS = blockSum1024(lps, red);
        const float pinv = 1.f / (PS + EPSF);
        #pragma unroll
        for (int i = 0; i < 8; ++i) xs[i] *= pinv;
    }
    // xs[] now = WW for this thread's 8 slots
    {
        float4 w0, w1;
        w0.x = xs[0]; w0.y = xs[1]; w0.z = xs[2]; w0.w = xs[3];
        w1.x = xs[4]; w1.y = xs[5]; w1.z = xs[6]; w1.w = xs[7];
        *(float4*)(ws + OFF_WW + bN + base) = w0;
        *(float4*)(ws + OFF_WW + bN + base + 4) = w1;
    }

    // ---------- R side ----------
    float dr[8] = {dr0.x, dr0.y, dr0.z, dr0.w, dr1.x, dr1.y, dr1.z, dr1.w};
    float c5[8] = {c50.x, c50.y, c50.z, c50.w, c51.x, c51.y, c51.z, c51.w};
    float nq[8] = {nq0.x, nq0.y, nq0.z, nq0.w, nq1.x, nq1.y, nq1.z, nq1.w};
    float e1[8] = {e10.x, e10.y, e10.z, e10.w, e11.x, e11.y, e11.z, e11.w};
    float e2[8] = {e20.x, e20.y, e20.z, e20.w, e21.x, e21.y, e21.z, e21.w};

    float lmax = -1e30f;
    #pragma unroll
    for (int i = 0; i < 8; ++i) {
        const float w = xs[i];
        const float d = dr[i] + w * (AK - c5[i]);
        float qq = nq[i] + 2.f * w * e1[i] + w * w * (e2[i] + A2);
        qq = fmaxf(qq, 0.f);
        const float x = beta_r * d / (sqrtf(qq) * kn_r + EPSF);
        xs[i] = x; lmax = fmaxf(lmax, x);
    }
    const float Mr = blockMax1024(lmax, red);
    float lsr = 0.f;
    #pragma unroll
    for (int i = 0; i < 8; ++i) { const float e = __expf(xs[i] - Mr); xs[i] = e; lsr += e; }
    const float Sr = blockSum1024(lsr, red);
    const float srinv = 1.f / Sr;
    pw[0] = pr0.x; pw[1] = pr0.y; pw[2] = pr0.z; pw[3] = pr0.w;
    pw[4] = pr1.x; pw[5] = pr1.y; pw[6] = pr1.z; pw[7] = pr1.w;
    __syncthreads();                  // all W-side buf reads complete
    #pragma unroll
    for (int i = 0; i < 8; ++i) buf[base + i] = g_r * xs[i] * srinv + (1.f - g_r) * pw[i];
    __syncthreads();
    {
        float nb[10];
        nb[0] = buf[(base + Nn - 1) & (Nn - 1)];
        #pragma unroll
        for (int i = 0; i < 8; ++i) nb[i + 1] = buf[base + i];
        nb[9] = buf[(base + 8) & (Nn - 1)];
        float lpr = 0.f;
        #pragma unroll
        for (int i = 0; i < 8; ++i) {
            const float wsv = s0r * nb[i + 2] + s1r * nb[i + 1] + s2r * nb[i];
            const float wp = __expf(gam_r * __logf(wsv));
            xs[i] = wp; lpr += wp;
        }
        const float PSr = blockSum1024(lpr, red);
        const float prinv = 1.f / (PSr + EPSF);
        float4 w0, w1;
        w0.x = xs[0] * prinv; w0.y = xs[1] * prinv; w0.z = xs[2] * prinv; w0.w = xs[3] * prinv;
        w1.x = xs[4] * prinv; w1.y = xs[5] * prinv; w1.z = xs[6] * prinv; w1.w = xs[7] * prinv;
        *(float4*)(ws + OFF_WR + bN + base) = w0;
        *(float4*)(ws + OFF_WR + bN + base + 4) = w1;
    }
}

// read-vector partials: recompute new_mem on the fly (second & last mem pass)
__global__ __launch_bounds__(256) void k_read(const float* __restrict__ mem,
                                              float* __restrict__ ws) {
    __shared__ float lds[4 * 64];
    const int b = blockIdx.x >> 5;
    const int chunk = blockIdx.x & 31;
    const int t = threadIdx.x;
    const int lane = t & 63, wv = t >> 6;
    const int q = lane & 15, r = lane >> 4;
    const float4 evv = *(const float4*)(ws + OFF_ER + (b << 6) + (q << 2));
    const float4 avv = *(const float4*)(ws + OFF_AD + (b << 6) + (q << 2));
    float a0 = 0.f, a1 = 0.f, a2 = 0.f, a3 = 0.f;
    const int base_n = chunk << 8;
    #pragma unroll 4
    for (int gi = wv; gi < 64; gi += 4) {
        const int n = base_n + (gi << 2) + r;
        const int row = b * Nn + n;
        const float4 mv = *(const float4*)(mem + ((size_t)row << 6) + (q << 2));
        const float w   = ws[OFF_WW + row];
        const float wrv = ws[OFF_WR + row];
        a0 = fmaf((mv.x * (1.f - w * evv.x) + w * avv.x), wrv, a0);
        a1 = fmaf((mv.y * (1.f - w * evv.y) + w * avv.y), wrv, a1);
        a2 = fmaf((mv.z * (1.f - w * evv.z) + w * avv.z), wrv, a2);
        a3 = fmaf((mv.w * (1.f - w * evv.w) + w * avv.w), wrv, a3);
    }
    #pragma unroll
    for (int m = 16; m <= 32; m <<= 1) {
        a0 += __shfl_xor(a0, m); a1 += __shfl_xor(a1, m);
        a2 += __shfl_xor(a2, m); a3 += __shfl_xor(a3, m);
    }
    if (r == 0) {
        lds[wv * 64 + q * 4 + 0] = a0; lds[wv * 64 + q * 4 + 1] = a1;
        lds[wv * 64 + q * 4 + 2] = a2; lds[wv * 64 + q * 4 + 3] = a3;
    }
    __syncthreads();
    if (t < 64) {
        ws[OFF_PT + blockIdx.x * 64 + t] = lds[t] + lds[64 + t] + lds[128 + t] + lds[192 + t];
    }
}

__global__ __launch_bounds__(64) void k_reduce(const float* __restrict__ ws,
                                               float* __restrict__ out) {
    const int b = blockIdx.x, d = threadIdx.x;
    float s = 0.f;
    #pragma unroll
    for (int i = 0; i < 32; ++i) s += ws[OFF_PT + ((b << 5) + i) * 64 + d];
    out[b * OUTW + 256 + d] = s;
}

extern "C" void kernel_launch(void* const* d_in, const int* in_sizes, int n_in,
                              void* d_out, int out_size, void* d_ws, size_t ws_size,
                              hipStream_t stream) {
    const float* x      = (const float*)d_in[0];
    const float* mem    = (const float*)d_in[1];
    const float* prw_r  = (const float*)d_in[2];
    const float* prw_w  = (const float*)d_in[3];
    const float* prv    = (const float*)d_in[4];

    float* ws  = (float*)d_ws;
    float* out = (float*)d_out;

    MainArgs a;
    a.x = x; a.prv = prv; a.mem = mem;
    a.Wc = (const float*)d_in[5];  a.bc = (const float*)d_in[6];
    a.Wk_r = (const float*)d_in[7];  a.bk_r = (const float*)d_in[8];
    a.Wb_r = (const float*)d_in[9];  a.bb_r = (const float*)d_in[10];
    a.Wg_r = (const float*)d_in[11]; a.bg_r = (const float*)d_in[12];
    a.Ws_r = (const float*)d_in[13]; a.bs_r = (const float*)d_in[14];
    a.Wgam_r = (const float*)d_in[15]; a.bgam_r = (const float*)d_in[16];
    a.Wk_w = (const float*)d_in[17]; a.bk_w = (const float*)d_in[18];
    a.Wb_w = (const float*)d_in[19]; a.bb_w = (const float*)d_in[20];
    a.Wg_w = (const float*)d_in[21]; a.bg_w = (const float*)d_in[22];
    a.Ws_w = (const float*)d_in[23]; a.bs_w = (const float*)d_in[24];
    a.Wgam_w = (const float*)d_in[25]; a.bgam_w = (const float*)d_in[26];
    a.We_w = (const float*)d_in[27]; a.be_w = (const float*)d_in[28];
    a.Wa_w = (const float*)d_in[29]; a.ba_w = (const float*)d_in[30];
    a.ws = ws; a.out = out;

    k_main<<<512, 256, 0, stream>>>(a);
    k_addrBoth<<<Bb, 1024, 0, stream>>>(ws, prw_w, prw_r);
    k_read<<<Bb * 32, 256, 0, stream>>>(mem, ws);
    k_reduce<<<Bb, 64, 0, stream>>>(ws, out);
}

// Round 5
// 89.161 us; speedup vs baseline: 1.2925x; 1.2925x over previous
//
#include <hip/hip_runtime.h>
#include <math.h>

#define Bb   64
#define Nn   8192
#define Dd   64
#define Cc   256
#define INn  128
#define CTRL 192
#define OUTW 320
#define EPSF 1e-8f
#define BN   (Bb*Nn)

// ---------------- workspace layout (floats) ----------------
#define OFF_P4 0                      // packed per-row {xw, dr, c5, nq}   [BN*4]
#define OFF_P2 (4*BN)                 // packed per-row {e1, e2}           [BN*2]
#define OFF_WW (6*BN)                 // write weights                     [BN]
#define OFF_WR (7*BN)                 // read weights                      [BN]
#define OFF_PT (8*BN)                 // read-vec partials                 [2048*64]
#define OFF_BM (OFF_PT + 2048*64)     // per-block max of x_w              [2048]
#define OFF_KW (OFF_BM + 2048)        // k_w                               [B*D]
#define OFF_KR (OFF_KW + Bb*Dd)       // k_r                               [B*D]
#define OFF_ER (OFF_KR + Bb*Dd)       // erase (post-sigmoid)              [B*D]
#define OFF_AD (OFF_ER + Bb*Dd)       // add (post-tanh)                   [B*D]
#define OFF_SC (OFF_AD + Bb*Dd)       // per-b scalars                     [B*16]
// per-b scalars: 0..3 beta_w,g_w,gam_w,knorm_w | 4..7 beta_r,g_r,gam_r,knorm_r
//                8..10 s_w | 11 AK=a.k_r | 12..14 s_r | 15 A2=|a|^2

__device__ __forceinline__ float softplusf(float x) {
    return (x > 20.f) ? x : log1pf(__expf(x));
}
__device__ __forceinline__ float sigmoidf(float x) {
    return 1.f / (1.f + __expf(-x));
}

// ---- block reductions for 1024 threads (16 waves), red[16] LDS ----
__device__ __forceinline__ float blockSum1024(float v, float* red) {
    #pragma unroll
    for (int m = 32; m >= 1; m >>= 1) v += __shfl_xor(v, m);
    __syncthreads();
    if ((threadIdx.x & 63) == 0) red[threadIdx.x >> 6] = v;
    __syncthreads();
    float s = 0.f;
    #pragma unroll
    for (int i = 0; i < 16; ++i) s += red[i];
    return s;
}
__device__ __forceinline__ float blockMax1024(float v, float* red) {
    #pragma unroll
    for (int m = 32; m >= 1; m >>= 1) v = fmaxf(v, __shfl_xor(v, m));
    __syncthreads();
    if ((threadIdx.x & 63) == 0) red[threadIdx.x >> 6] = v;
    __syncthreads();
    float s = -1e30f;
    #pragma unroll
    for (int i = 0; i < 16; ++i) s = fmaxf(s, red[i]);
    return s;
}

struct SetupArgs {
    const float *x, *prv, *Wc, *bc;
    const float *Wk_r, *bk_r, *Wb_r, *bb_r, *Wg_r, *bg_r, *Ws_r, *bs_r, *Wgam_r, *bgam_r;
    const float *Wk_w, *bk_w, *Wb_w, *bb_w, *Wg_w, *bg_w, *Ws_w, *bs_w, *Wgam_w, *bgam_w;
    const float *We_w, *be_w, *Wa_w, *ba_w;
    float *ws, *out;
};

// one block per batch: controller GEMM + projections + batched scalar reductions
__global__ __launch_bounds__(256) void k_setup(SetupArgs a) {
    __shared__ float ci[CTRL];
    __shared__ float h[Cc];
    __shared__ alignas(16) float kbuf[128];
    __shared__ alignas(16) float abuf[64];
    __shared__ float red[4][16];
    __shared__ float sums[16];
    const int b = blockIdx.x, t = threadIdx.x;

    if (t < INn)       ci[t] = a.x[b * INn + t];
    else if (t < CTRL) ci[t] = a.prv[b * Dd + (t - INn)];
    __syncthreads();

    float acc = a.bc[t];
    #pragma unroll 16
    for (int i = 0; i < CTRL; ++i) acc += ci[i] * a.Wc[i * Cc + t];
    const float hv = fmaxf(acc, 0.f);
    h[t] = hv;
    a.out[b * OUTW + t] = hv;
    __syncthreads();

    {
        const int job = t >> 6, d = t & 63;
        const float* W  = (job == 0) ? a.Wk_w : (job == 1) ? a.Wk_r : (job == 2) ? a.We_w : a.Wa_w;
        const float* bs = (job == 0) ? a.bk_w : (job == 1) ? a.bk_r : (job == 2) ? a.be_w : a.ba_w;
        float p = bs[d];
        #pragma unroll 16
        for (int c = 0; c < Cc; ++c) p += h[c] * W[c * Dd + d];
        if (job == 0)      { a.ws[OFF_KW + b * Dd + d] = p; kbuf[d] = p; }
        else if (job == 1) { a.ws[OFF_KR + b * Dd + d] = p; kbuf[64 + d] = p; }
        else if (job == 2) { a.ws[OFF_ER + b * Dd + d] = sigmoidf(p); }
        else               { const float ad = tanhf(p); a.ws[OFF_AD + b * Dd + d] = ad; abuf[d] = ad; }
    }
    __syncthreads();

    float v[16];
    v[0] = hv * a.Wb_w[t];  v[1] = hv * a.Wg_w[t];  v[2] = hv * a.Wgam_w[t];
    v[3] = hv * a.Ws_w[t * 3 + 0]; v[4] = hv * a.Ws_w[t * 3 + 1]; v[5] = hv * a.Ws_w[t * 3 + 2];
    v[6] = hv * a.Wb_r[t];  v[7] = hv * a.Wg_r[t];  v[8] = hv * a.Wgam_r[t];
    v[9] = hv * a.Ws_r[t * 3 + 0]; v[10] = hv * a.Ws_r[t * 3 + 1]; v[11] = hv * a.Ws_r[t * 3 + 2];
    v[12] = (t < 64) ? kbuf[t] * kbuf[t] : 0.f;
    v[13] = (t >= 64 && t < 128) ? kbuf[t] * kbuf[t] : 0.f;
    v[14] = (t < 64) ? abuf[t] * kbuf[64 + t] : 0.f;
    v[15] = (t < 64) ? abuf[t] * abuf[t] : 0.f;
    #pragma unroll
    for (int k = 0; k < 16; ++k) {
        #pragma unroll
        for (int m = 32; m >= 1; m >>= 1) v[k] += __shfl_xor(v[k], m);
    }
    if ((t & 63) == 0) {
        #pragma unroll
        for (int k = 0; k < 16; ++k) red[t >> 6][k] = v[k];
    }
    __syncthreads();
    if (t < 16) sums[t] = red[0][t] + red[1][t] + red[2][t] + red[3][t];
    __syncthreads();

    if (t == 0) {
        float* sc = a.ws + OFF_SC + b * 16;
        sc[0] = softplusf(sums[0] + a.bb_w[0]);
        sc[1] = sigmoidf(sums[1] + a.bg_w[0]);
        sc[2] = softplusf(sums[2] + a.bgam_w[0]) + 1.f;
        sc[3] = sqrtf(sums[12]);
        sc[4] = softplusf(sums[6] + a.bb_r[0]);
        sc[5] = sigmoidf(sums[7] + a.bg_r[0]);
        sc[6] = softplusf(sums[8] + a.bgam_r[0]) + 1.f;
        sc[7] = sqrtf(sums[13]);
        {
            const float v0 = sums[3] + a.bs_w[0], v1 = sums[4] + a.bs_w[1], v2 = sums[5] + a.bs_w[2];
            const float m = fmaxf(fmaxf(v0, v1), v2);
            const float e0 = __expf(v0 - m), e1 = __expf(v1 - m), e2 = __expf(v2 - m);
            const float s = e0 + e1 + e2;
            sc[8] = e0 / s; sc[9] = e1 / s; sc[10] = e2 / s;
        }
        sc[11] = sums[14];
        {
            const float v0 = sums[9] + a.bs_r[0], v1 = sums[10] + a.bs_r[1], v2 = sums[11] + a.bs_r[2];
            const float m = fmaxf(fmaxf(v0, v1), v2);
            const float e0 = __expf(v0 - m), e1 = __expf(v1 - m), e2 = __expf(v2 - m);
            const float s = e0 + e1 + e2;
            sc[12] = e0 / s; sc[13] = e1 / s; sc[14] = e2 / s;
        }
        sc[15] = sums[15];
    }
}

// streaming pass: 2048 blocks x 256 thr (32 waves/CU). 8 lanes per row, 8 cols/lane.
// Reduction = 3 butterfly levels per 8 rows. Outputs packed AoS per row.
__global__ __launch_bounds__(256) void k_pass1(const float* __restrict__ mem,
                                               float* __restrict__ ws) {
    __shared__ float redmax[4];
    const int t = threadIdx.x;
    const int wv = t >> 6, lane = t & 63;
    const int cg = lane & 7;          // col group 0..7
    const int rr = lane >> 3;         // row within 8
    const int wbase = blockIdx.x * 256 + wv * 64;   // 64 rows per wave
    const int b = wbase >> 13;
    const int cb = cg << 3;           // col base

    const float4 kwA = *(const float4*)(ws + OFF_KW + (b << 6) + cb);
    const float4 kwB = *(const float4*)(ws + OFF_KW + (b << 6) + cb + 4);
    const float4 krA = *(const float4*)(ws + OFF_KR + (b << 6) + cb);
    const float4 krB = *(const float4*)(ws + OFF_KR + (b << 6) + cb + 4);
    const float4 evA = *(const float4*)(ws + OFF_ER + (b << 6) + cb);
    const float4 evB = *(const float4*)(ws + OFF_ER + (b << 6) + cb + 4);
    const float4 avA = *(const float4*)(ws + OFF_AD + (b << 6) + cb);
    const float4 avB = *(const float4*)(ws + OFF_AD + (b << 6) + cb + 4);
    const float beta = ws[OFF_SC + b * 16 + 0];
    const float kn   = ws[OFF_SC + b * 16 + 3];

    float lmax = -1e30f;
    #pragma unroll 2
    for (int it = 0; it < 8; ++it) {
        const int row = wbase + (it << 3) + rr;
        const float* mp = mem + ((size_t)row << 6) + cb;
        const float4 m0 = *(const float4*)(mp);
        const float4 m1 = *(const float4*)(mp + 4);
        float dw = 0.f, dr = 0.f, nq = 0.f, e1 = 0.f, e2 = 0.f, c5 = 0.f;
        #define ACC(mv, kwv, krv, evv, avv) { \
            const float me = (mv) * (evv); \
            dw = fmaf((mv), (kwv), dw); \
            dr = fmaf((mv), (krv), dr); \
            nq = fmaf((mv), (mv), nq); \
            e1 = fmaf((mv), (avv) - me, e1); \
            e2 = fmaf(me, fmaf(-2.f, (avv), me), e2); \
            c5 = fmaf(me, (krv), c5); }
        ACC(m0.x, kwA.x, krA.x, evA.x, avA.x)
        ACC(m0.y, kwA.y, krA.y, evA.y, avA.y)
        ACC(m0.z, kwA.z, krA.z, evA.z, avA.z)
        ACC(m0.w, kwA.w, krA.w, evA.w, avA.w)
        ACC(m1.x, kwB.x, krB.x, evB.x, avB.x)
        ACC(m1.y, kwB.y, krB.y, evB.y, avB.y)
        ACC(m1.z, kwB.z, krB.z, evB.z, avB.z)
        ACC(m1.w, kwB.w, krB.w, evB.w, avB.w)
        #undef ACC
        #pragma unroll
        for (int mk = 1; mk <= 4; mk <<= 1) {
            dw += __shfl_xor(dw, mk); dr += __shfl_xor(dr, mk);
            nq += __shfl_xor(nq, mk); e1 += __shfl_xor(e1, mk);
            e2 += __shfl_xor(e2, mk); c5 += __shfl_xor(c5, mk);
        }
        // butterfly -> every lane in the 8-lane group has the full sums
        const float xw = beta * dw / (sqrtf(nq) * kn + EPSF);
        lmax = fmaxf(lmax, xw);
        if (cg == 0) {
            float4 p4; p4.x = xw; p4.y = dr; p4.z = c5; p4.w = nq;
            *(float4*)(ws + OFF_P4 + ((size_t)row << 2)) = p4;
            float2 p2; p2.x = e1; p2.y = e2;
            *(float2*)(ws + OFF_P2 + ((size_t)row << 1)) = p2;
        }
    }
    // wave max across the 8 row-groups (cols duplicated -> masks 8,16,32 suffice)
    lmax = fmaxf(lmax, __shfl_xor(lmax, 8));
    lmax = fmaxf(lmax, __shfl_xor(lmax, 16));
    lmax = fmaxf(lmax, __shfl_xor(lmax, 32));
    if (lane == 0) redmax[wv] = lmax;
    __syncthreads();
    if (t == 0)
        ws[OFF_BM + blockIdx.x] = fmaxf(fmaxf(redmax[0], redmax[1]),
                                        fmaxf(redmax[2], redmax[3]));
}

// fused W+R addressing: one block (1024 thr) per batch; thread t owns rows [8t, 8t+8)
__global__ __launch_bounds__(1024, 4) void k_addrBoth(float* __restrict__ ws,
                                                      const float* __restrict__ prevw_w,
                                                      const float* __restrict__ prevw_r) {
    __shared__ float buf[Nn];
    __shared__ float red[16];
    const int b = blockIdx.x, t = threadIdx.x;
    const int bN = b * Nn;
    const int base = t << 3;
    const float* sc = ws + OFF_SC + b * 16;
    const float g_w = sc[1], gam_w = sc[2];
    const float s0w = sc[8], s1w = sc[9], s2w = sc[10];
    const float beta_r = sc[4], g_r = sc[5], gam_r = sc[6], kn_r = sc[7];
    const float AK = sc[11], A2 = sc[15];
    const float s0r = sc[12], s1r = sc[13], s2r = sc[14];

    float M = -1e30f;
    #pragma unroll
    for (int i = 0; i < 32; ++i) M = fmaxf(M, ws[OFF_BM + b * 32 + i]);

    // prefetch all per-row data (latency hides under W-side softmax/shift)
    float4 p4[8]; float2 p2[8];
    #pragma unroll
    for (int i = 0; i < 8; ++i) p4[i] = *(const float4*)(ws + OFF_P4 + ((size_t)(bN + base + i) << 2));
    #pragma unroll
    for (int i = 0; i < 8; ++i) p2[i] = *(const float2*)(ws + OFF_P2 + ((size_t)(bN + base + i) << 1));
    const float4 pw0 = *(const float4*)(prevw_w + bN + base);
    const float4 pw1 = *(const float4*)(prevw_w + bN + base + 4);
    const float4 pr0 = *(const float4*)(prevw_r + bN + base);
    const float4 pr1 = *(const float4*)(prevw_r + bN + base + 4);

    // ---------- W side ----------
    float xs[8];
    float pw[8] = {pw0.x, pw0.y, pw0.z, pw0.w, pw1.x, pw1.y, pw1.z, pw1.w};
    float lsum = 0.f;
    #pragma unroll
    for (int i = 0; i < 8; ++i) { const float e = __expf(p4[i].x - M); xs[i] = e; lsum += e; }
    const float S = blockSum1024(lsum, red);
    const float sinv = 1.f / S;
    #pragma unroll
    for (int i = 0; i < 8; ++i) buf[base + i] = g_w * xs[i] * sinv + (1.f - g_w) * pw[i];
    __syncthreads();
    {
        float nb[10];
        nb[0] = buf[(base + Nn - 1) & (Nn - 1)];
        #pragma unroll
        for (int i = 0; i < 8; ++i) nb[i + 1] = buf[base + i];
        nb[9] = buf[(base + 8) & (Nn - 1)];
        float lps = 0.f;
        #pragma unroll
        for (int i = 0; i < 8; ++i) {
            const float wsv = s0w * nb[i + 2] + s1w * nb[i + 1] + s2w * nb[i];
            const float wp = __expf(gam_w * __logf(wsv));
            xs[i] = wp; lps += wp;
        }
        const float PS = blockSum1024(lps, red);
        const float pinv = 1.f / (PS + EPSF);
        #pragma unroll
        for (int i = 0; i < 8; ++i) xs[i] *= pinv;
    }
    {
        float4 w0, w1;
        w0.x = xs[0]; w0.y = xs[1]; w0.z = xs[2]; w0.w = xs[3];
        w1.x = xs[4]; w1.y = xs[5]; w1.z = xs[6]; w1.w = xs[7];
        *(float4*)(ws + OFF_WW + bN + base) = w0;
        *(float4*)(ws + OFF_WW + bN + base + 4) = w1;
    }

    // ---------- R side ----------
    float lmax = -1e30f;
    #pragma unroll
    for (int i = 0; i < 8; ++i) {
        const float w = xs[i];
        const float d = p4[i].y + w * (AK - p4[i].z);
        float qq = p4[i].w + 2.f * w * p2[i].x + w * w * (p2[i].y + A2);
        qq = fmaxf(qq, 0.f);
        const float x = beta_r * d / (sqrtf(qq) * kn_r + EPSF);
        xs[i] = x; lmax = fmaxf(lmax, x);
    }
    const float Mr = blockMax1024(lmax, red);
    float lsr = 0.f;
    #pragma unroll
    for (int i = 0; i < 8; ++i) { const float e = __expf(xs[i] - Mr); xs[i] = e; lsr += e; }
    const float Sr = blockSum1024(lsr, red);
    const float srinv = 1.f / Sr;
    float prv[8] = {pr0.x, pr0.y, pr0.z, pr0.w, pr1.x, pr1.y, pr1.z, pr1.w};
    __syncthreads();                  // all W-side buf reads complete
    #pragma unroll
    for (int i = 0; i < 8; ++i) buf[base + i] = g_r * xs[i] * srinv + (1.f - g_r) * prv[i];
    __syncthreads();
    {
        float nb[10];
        nb[0] = buf[(base + Nn - 1) & (Nn - 1)];
        #pragma unroll
        for (int i = 0; i < 8; ++i) nb[i + 1] = buf[base + i];
        nb[9] = buf[(base + 8) & (Nn - 1)];
        float lpr = 0.f;
        #pragma unroll
        for (int i = 0; i < 8; ++i) {
            const float wsv = s0r * nb[i + 2] + s1r * nb[i + 1] + s2r * nb[i];
            const float wp = __expf(gam_r * __logf(wsv));
            xs[i] = wp; lpr += wp;
        }
        const float PSr = blockSum1024(lpr, red);
        const float prinv = 1.f / (PSr + EPSF);
        float4 w0, w1;
        w0.x = xs[0] * prinv; w0.y = xs[1] * prinv; w0.z = xs[2] * prinv; w0.w = xs[3] * prinv;
        w1.x = xs[4] * prinv; w1.y = xs[5] * prinv; w1.z = xs[6] * prinv; w1.w = xs[7] * prinv;
        *(float4*)(ws + OFF_WR + bN + base) = w0;
        *(float4*)(ws + OFF_WR + bN + base + 4) = w1;
    }
}

// read-vector partials: recompute new_mem on the fly (second & last mem pass)
__global__ __launch_bounds__(256) void k_read(const float* __restrict__ mem,
                                              float* __restrict__ ws) {
    __shared__ float lds[4 * 64];
    const int b = blockIdx.x >> 5;
    const int chunk = blockIdx.x & 31;
    const int t = threadIdx.x;
    const int lane = t & 63, wv = t >> 6;
    const int q = lane & 15, r = lane >> 4;
    const float4 evv = *(const float4*)(ws + OFF_ER + (b << 6) + (q << 2));
    const float4 avv = *(const float4*)(ws + OFF_AD + (b << 6) + (q << 2));
    float a0 = 0.f, a1 = 0.f, a2 = 0.f, a3 = 0.f;
    const int base_n = chunk << 8;
    #pragma unroll 4
    for (int gi = wv; gi < 64; gi += 4) {
        const int n = base_n + (gi << 2) + r;
        const int row = b * Nn + n;
        const float4 mv = *(const float4*)(mem + ((size_t)row << 6) + (q << 2));
        const float w   = ws[OFF_WW + row];
        const float wrv = ws[OFF_WR + row];
        a0 = fmaf((mv.x * (1.f - w * evv.x) + w * avv.x), wrv, a0);
        a1 = fmaf((mv.y * (1.f - w * evv.y) + w * avv.y), wrv, a1);
        a2 = fmaf((mv.z * (1.f - w * evv.z) + w * avv.z), wrv, a2);
        a3 = fmaf((mv.w * (1.f - w * evv.w) + w * avv.w), wrv, a3);
    }
    #pragma unroll
    for (int m = 16; m <= 32; m <<= 1) {
        a0 += __shfl_xor(a0, m); a1 += __shfl_xor(a1, m);
        a2 += __shfl_xor(a2, m); a3 += __shfl_xor(a3, m);
    }
    if (r == 0) {
        lds[wv * 64 + q * 4 + 0] = a0; lds[wv * 64 + q * 4 + 1] = a1;
        lds[wv * 64 + q * 4 + 2] = a2; lds[wv * 64 + q * 4 + 3] = a3;
    }
    __syncthreads();
    if (t < 64) {
        ws[OFF_PT + blockIdx.x * 64 + t] = lds[t] + lds[64 + t] + lds[128 + t] + lds[192 + t];
    }
}

__global__ __launch_bounds__(64) void k_reduce(const float* __restrict__ ws,
                                               float* __restrict__ out) {
    const int b = blockIdx.x, d = threadIdx.x;
    float s = 0.f;
    #pragma unroll
    for (int i = 0; i < 32; ++i) s += ws[OFF_PT + ((b << 5) + i) * 64 + d];
    out[b * OUTW + 256 + d] = s;
}

extern "C" void kernel_launch(void* const* d_in, const int* in_sizes, int n_in,
                              void* d_out, int out_size, void* d_ws, size_t ws_size,
                              hipStream_t stream) {
    const float* x      = (const float*)d_in[0];
    const float* mem    = (const float*)d_in[1];
    const float* prw_r  = (const float*)d_in[2];
    const float* prw_w  = (const float*)d_in[3];
    const float* prv    = (const float*)d_in[4];

    float* ws  = (float*)d_ws;
    float* out = (float*)d_out;

    SetupArgs a;
    a.x = x; a.prv = prv;
    a.Wc = (const float*)d_in[5];  a.bc = (const float*)d_in[6];
    a.Wk_r = (const float*)d_in[7];  a.bk_r = (const float*)d_in[8];
    a.Wb_r = (const float*)d_in[9];  a.bb_r = (const float*)d_in[10];
    a.Wg_r = (const float*)d_in[11]; a.bg_r = (const float*)d_in[12];
    a.Ws_r = (const float*)d_in[13]; a.bs_r = (const float*)d_in[14];
    a.Wgam_r = (const float*)d_in[15]; a.bgam_r = (const float*)d_in[16];
    a.Wk_w = (const float*)d_in[17]; a.bk_w = (const float*)d_in[18];
    a.Wb_w = (const float*)d_in[19]; a.bb_w = (const float*)d_in[20];
    a.Wg_w = (const float*)d_in[21]; a.bg_w = (const float*)d_in[22];
    a.Ws_w = (const float*)d_in[23]; a.bs_w = (const float*)d_in[24];
    a.Wgam_w = (const float*)d_in[25]; a.bgam_w = (const float*)d_in[26];
    a.We_w = (const float*)d_in[27]; a.be_w = (const float*)d_in[28];
    a.Wa_w = (const float*)d_in[29]; a.ba_w = (const float*)d_in[30];
    a.ws = ws; a.out = out;

    k_setup<<<Bb, 256, 0, stream>>>(a);
    k_pass1<<<2048, 256, 0, stream>>>(mem, ws);
    k_addrBoth<<<Bb, 1024, 0, stream>>>(ws, prw_w, prw_r);
    k_read<<<Bb * 32, 256, 0, stream>>>(mem, ws);
    k_reduce<<<Bb, 64, 0, stream>>>(ws, out);
}